// Round 6
// baseline (434.839 us; speedup 1.0000x reference)
//
#include <hip/hip_runtime.h>
#include <hip/hip_cooperative_groups.h>
#include <math.h>
#include <stdint.h>

namespace cg = cooperative_groups;

#define Bn   2
#define Nn   1024
#define DIMn 512
#define NHn  8
#define HDn  64
#define QKVS 1536
#define EPSF 1e-7f
#define NBLK 256
#define NTHR 512

typedef __attribute__((ext_vector_type(8))) short short8;
typedef __attribute__((ext_vector_type(4))) float floatx4;
typedef __attribute__((ext_vector_type(4))) float fx4;
typedef __attribute__((ext_vector_type(4))) unsigned short usx4;
typedef unsigned short ushort_t;

// ---------------- bf16 helpers (RNE) ----------------
__device__ __forceinline__ unsigned short f2bf(float f) {
  union { float f; uint32_t u; } v; v.f = f;
  uint32_t u = v.u;
  return (unsigned short)((u + 0x7FFFu + ((u >> 16) & 1u)) >> 16);
}
__device__ __forceinline__ float bf2f(unsigned short h) {
  union { uint32_t u; float f; } v; v.u = ((uint32_t)h) << 16;
  return v.f;
}

__device__ __forceinline__ float wsum(float v) {
#pragma unroll
  for (int m = 32; m >= 1; m >>= 1) v += __shfl_xor(v, m, 64);
  return v;
}

__device__ __forceinline__ float gelu_tanh(float x) {
  const float k0 = 0.7978845608028654f;
  float x3 = x * x * x;
  return 0.5f * x * (1.f + tanhf(k0 * (x + 0.044715f * x3)));
}

__device__ __forceinline__ void glds16(const unsigned short* g, unsigned short* l) {
  __builtin_amdgcn_global_load_lds((const __attribute__((address_space(1))) void*)g,
                                   (__attribute__((address_space(3))) void*)l, 16, 0, 0);
}

// ---------------- LN row: 512 threads, 1 elem/thread ----------------
__device__ void ln_row(const float* __restrict__ xr, const float* __restrict__ g,
                       const float* __restrict__ be, unsigned short* __restrict__ yhi,
                       unsigned short* __restrict__ ylo, float* red, int tid) {
  float v = xr[tid];
  float s = wsum(v), s2 = wsum(v * v);
  int wv = tid >> 6;
  if ((tid & 63) == 0) { red[wv] = s; red[8 + wv] = s2; }
  __syncthreads();
  s = 0.f; s2 = 0.f;
#pragma unroll
  for (int i = 0; i < 8; ++i) { s += red[i]; s2 += red[8 + i]; }
  __syncthreads();  // red reusable next row
  float mean = s * (1.f / DIMn);
  float var = s2 * (1.f / DIMn) - mean * mean;
  float rstd = rsqrtf(var + 1e-6f);
  float o = (v - mean) * rstd * g[tid] + be[tid];
  unsigned short h = f2bf(o);
  yhi[tid] = h;
  if (ylo) ylo[tid] = f2bf(o - bf2f(h));
}

// ---------------- plain 64x64 GEMM unit, 8 waves, BKT=64, double-buffered ----------------
// EPI: 0=bias, 1=bias+res, 2=bias+gelu.
template <int EPI, int OUTBF16>
__device__ void gemm_unit(const unsigned short* __restrict__ A,
                          const unsigned short* __restrict__ B,
                          const float* __restrict__ bias, const float* __restrict__ res,
                          void* __restrict__ outp, int bm, int bn, int N, int K,
                          char* LU, int tid) {
  constexpr int BKT = 64;
  constexpr int AE = 64 * BKT;   // 4096 shorts
  constexpr int STG = 2 * AE;    // A+B per stage
  unsigned short* sb = (unsigned short*)LU;
  int lane = tid & 63, wid = tid >> 6;
  int wm = (wid >> 1) * 16, wn = (wid & 1) * 32;
  int m16 = lane & 15, kg = lane >> 4;
  floatx4 acc[2];
  { floatx4 z = {0.f, 0.f, 0.f, 0.f}; acc[0] = z; acc[1] = z; }
  const unsigned short* ap = A + (size_t)bm * K;
  const unsigned short* bp = B + (size_t)bn * K;

  auto stage = [&](int k0, unsigned short* buf) {
    int c = tid;  // 512 A-chunks + 512 B-chunks
    int row = c >> 3, kk = (c & 7) * 8;
    glds16(ap + (size_t)row * K + k0 + kk, buf + c * 8);
    glds16(bp + (size_t)row * K + k0 + kk, buf + AE + c * 8);
  };

  const int NT = K / BKT;
  stage(0, sb);
  __syncthreads();
  int cur = 0;
  for (int t = 0; t < NT; ++t) {
    unsigned short* buf = sb + cur * STG;
    int nxt = cur ^ 1;
    if (t + 1 < NT) stage((t + 1) * BKT, sb + nxt * STG);
#pragma unroll
    for (int ks = 0; ks < 2; ++ks) {
      short8 ah = *(const short8*)&buf[(wm + m16) * BKT + ks * 32 + kg * 8];
#pragma unroll
      for (int j = 0; j < 2; ++j) {
        short8 bh = *(const short8*)&buf[AE + (wn + j * 16 + m16) * BKT + ks * 32 + kg * 8];
        acc[j] = __builtin_amdgcn_mfma_f32_16x16x32_bf16(ah, bh, acc[j], 0, 0, 0);
      }
    }
    __syncthreads();
    cur = nxt;
  }

  // epilogue: bounce to LDS, coalesced stores
  float* Cs = (float*)LU;
  constexpr int CST = 68;
#pragma unroll
  for (int j = 0; j < 2; ++j)
#pragma unroll
    for (int r = 0; r < 4; ++r)
      Cs[(wm + kg * 4 + r) * CST + wn + j * 16 + m16] = acc[j][r];
  __syncthreads();
  for (int t = tid; t < 1024; t += NTHR) {
    int row = t >> 4, col = (t & 15) << 2;
    fx4 v = *(const fx4*)&Cs[row * CST + col];
    fx4 bs = *(const fx4*)&bias[bn + col];
    v = v + bs;
    size_t gidx = (size_t)(bm + row) * N + bn + col;
    if constexpr (EPI == 1) {
      fx4 rr = *(const fx4*)&res[gidx];
      v = v + rr;
    }
    if constexpr (EPI == 2) {
      v.x = gelu_tanh(v.x); v.y = gelu_tanh(v.y);
      v.z = gelu_tanh(v.z); v.w = gelu_tanh(v.w);
    }
    if constexpr (OUTBF16) {
      usx4 h;
      h.x = f2bf(v.x); h.y = f2bf(v.y); h.z = f2bf(v.z); h.w = f2bf(v.w);
      *(usx4*)((unsigned short*)outp + gidx) = h;
    } else {
      *(fx4*)((float*)outp + gidx) = v;
    }
  }
  __syncthreads();  // LU reusable by next unit
}

// ---------------- QKV 64x64 unit: hybrid split-bf16, BKT=32, double-buffered -----------
__device__ void qkv_unit(const unsigned short* __restrict__ Ahi,
                         const unsigned short* __restrict__ Alo,
                         const unsigned short* __restrict__ Bhi,
                         const unsigned short* __restrict__ Blo,
                         const float* __restrict__ bias, float* __restrict__ outp,
                         int u, int tid, char* LU) {
  constexpr int BKT = 32, K = 512, N = QKVS;
  constexpr int AE = 64 * BKT;   // 2048 shorts
  constexpr int STG = 4 * AE;    // AsHi|AsLo|BsHi|BsLo
  unsigned short* sb = (unsigned short*)LU;
  int mt = u / 24, ntl = u % 24;
  int bm = mt * 64, bn = ntl * 64;
  bool dos = bn < 1024;
  int lane = tid & 63, wid = tid >> 6;
  int wm = (wid >> 1) * 16, wn = (wid & 1) * 32;
  int m16 = lane & 15, kg = lane >> 4;
  floatx4 acc[2];
  { floatx4 z = {0.f, 0.f, 0.f, 0.f}; acc[0] = z; acc[1] = z; }
  const unsigned short* aph = Ahi + (size_t)bm * K;
  const unsigned short* bph = Bhi + (size_t)bn * K;
  const unsigned short* apl = Alo + (size_t)bm * K;
  const unsigned short* bpl = Blo + (size_t)bn * K;

  auto stage = [&](int k0, unsigned short* buf) {
    int c = tid & 255;
    int row = c >> 2, kk = (c & 3) * 8;
    if (tid < 256) {
      glds16(aph + (size_t)row * K + k0 + kk, buf + c * 8);
      if (dos) glds16(apl + (size_t)row * K + k0 + kk, buf + AE + c * 8);
    } else {
      glds16(bph + (size_t)row * K + k0 + kk, buf + 2 * AE + c * 8);
      if (dos) glds16(bpl + (size_t)row * K + k0 + kk, buf + 3 * AE + c * 8);
    }
  };

  stage(0, sb);
  __syncthreads();
  int cur = 0;
  for (int t = 0; t < 16; ++t) {
    unsigned short* buf = sb + cur * STG;
    int nxt = cur ^ 1;
    if (t + 1 < 16) stage((t + 1) * BKT, sb + nxt * STG);
    short8 ah = *(const short8*)&buf[(wm + m16) * BKT + kg * 8];
    short8 al;
    if (dos) al = *(const short8*)&buf[AE + (wm + m16) * BKT + kg * 8];
#pragma unroll
    for (int j = 0; j < 2; ++j) {
      int r = wn + j * 16 + m16;
      short8 bh = *(const short8*)&buf[2 * AE + r * BKT + kg * 8];
      acc[j] = __builtin_amdgcn_mfma_f32_16x16x32_bf16(ah, bh, acc[j], 0, 0, 0);
      if (dos) {
        short8 bl = *(const short8*)&buf[3 * AE + r * BKT + kg * 8];
        acc[j] = __builtin_amdgcn_mfma_f32_16x16x32_bf16(al, bh, acc[j], 0, 0, 0);
        acc[j] = __builtin_amdgcn_mfma_f32_16x16x32_bf16(ah, bl, acc[j], 0, 0, 0);
      }
    }
    __syncthreads();
    cur = nxt;
  }

  float* Cs = (float*)LU;
  constexpr int CST = 68;
#pragma unroll
  for (int j = 0; j < 2; ++j)
#pragma unroll
    for (int r = 0; r < 4; ++r)
      Cs[(wm + kg * 4 + r) * CST + wn + j * 16 + m16] = acc[j][r];
  __syncthreads();
  for (int t = tid; t < 1024; t += NTHR) {
    int row = t >> 4, col = (t & 15) << 2;
    fx4 v = *(const fx4*)&Cs[row * CST + col];
    fx4 bs = *(const fx4*)&bias[bn + col];
    v = v + bs;
    *(fx4*)(outp + (size_t)(bm + row) * N + bn + col) = v;
  }
  __syncthreads();
}

// ---------------- attn unit (512 threads), LDS via manual union ----------------
__device__ void attn_unit(const float* __restrict__ qkv, const float* __restrict__ fcos,
                          const float* __restrict__ fsin, const float* __restrict__ cvec,
                          const float* __restrict__ geo, const float* __restrict__ hash,
                          unsigned short* __restrict__ attn_out, int bidu, int tid,
                          char* LU) {
  unsigned short* Qhi = (unsigned short*)LU;      // [32][72]
  unsigned short* Qlo = Qhi + 32 * 72;
  unsigned short* Khi = Qlo + 32 * 72;            // [96][72]
  unsigned short* Klo = Khi + 96 * 72;
  unsigned short* Vt  = Klo + 96 * 72;            // [64][104]
  unsigned short* Pb  = Vt + 64 * 104;            // [32][104]
  float* Sf  = (float*)(Pb + 32 * 104);           // [32][97]
  float* x2s = Sf + 32 * 97;
  float* bxs = x2s + 32;
  float* y2s = bxs + 32;
  float* gys = y2s + 96;

  int lane = tid & 63, wv = tid >> 6;
  int nt = bidu & 31, h = (bidu >> 5) & 7, b = bidu >> 8;
  int n0 = nt * 32;
  float c = cvec[b];
  float sqc = sqrtf(c);
  float rsqc = 1.f / sqc;
  float gs = geo[h];
  int dr = lane & 31;
  bool hih = lane >= 32;
  const float LOG9 = 2.1972245773362196f;
  float hofr = hash[h * HDn + dr] * LOG9;
  float hofi = hash[h * HDn + dr + 32] * LOG9;

  __syncthreads();  // protect LDS reuse from previous unit/phase

  for (int i = tid; i < 32 * 52; i += NTHR) ((uint32_t*)Pb)[i] = 0u;

  // stage Q (4 rows/wave)
#pragma unroll
  for (int i = 0; i < 4; ++i) {
    int q = wv * 4 + i;
    int n = n0 + q;
    size_t bas = (size_t)(b * Nn + n) * QKVS + h * HDn;
    float qr = qkv[bas + dr] + hofr;
    float qi = qkv[bas + dr + 32] + hofi;
    float cs = fcos[n * 32 + dr], sn = fsin[n * 32 + dr];
    float qv = hih ? (qr * sn + qi * cs) : (qr * cs - qi * sn);
    float nq = sqrtf(wsum(qv * qv));
    float sq = fmaxf(nq, EPSF);
    float t = sqc * sq;
    float em = expf(-2.f * t);
    float opem = 1.f + em;
    float mag = ((1.f - em) / opem) * rsqc;
    float sech2 = 4.f * em / (opem * opem);
    float oq = (nq < EPSF) ? 0.f : mag * (qv / sq);
    unsigned short hh = f2bf(oq);
    Qhi[q * 72 + lane] = hh;
    Qlo[q * 72 + lane] = f2bf(oq - bf2f(hh));
    if (lane == 0) {
      x2s[q] = (nq < EPSF) ? 0.f : mag * mag;
      bxs[q] = (nq < EPSF) ? 1.f : sech2;
    }
  }
  // stage K (12 rows/wave) + V^T
#pragma unroll 4
  for (int i = 0; i < 12; ++i) {
    int r = wv * 12 + i;
    int gi = n0 - 64 + r;
    float ok = 0.f, vf = 0.f, y2 = 0.f, gy = 1.f;
    if (gi >= 0) {
      size_t bas = (size_t)(b * Nn + gi) * QKVS + h * HDn;
      float kr = qkv[bas + 512 + dr];
      float ki = qkv[bas + 512 + dr + 32];
      vf = qkv[bas + 1024 + lane];
      float cs = fcos[gi * 32 + dr], sn = fsin[gi * 32 + dr];
      float kv = hih ? (kr * sn + ki * cs) : (kr * cs - ki * sn);
      float nk = sqrtf(wsum(kv * kv));
      float sk = fmaxf(nk, EPSF);
      float t = sqc * sk;
      float em = expf(-2.f * t);
      float opem = 1.f + em;
      float mag = ((1.f - em) / opem) * rsqc;
      float sech2 = 4.f * em / (opem * opem);
      ok = (nk < EPSF) ? 0.f : mag * (kv / sk);
      y2 = (nk < EPSF) ? 0.f : mag * mag;
      gy = (nk < EPSF) ? 1.f : sech2;
    }
    unsigned short hh = f2bf(ok);
    Khi[r * 72 + lane] = hh;
    Klo[r * 72 + lane] = f2bf(ok - bf2f(hh));
    Vt[lane * 104 + r] = f2bf(vf);
    if (lane == 0) { y2s[r] = y2; gys[r] = gy; }
  }
  __syncthreads();

  // S = Q K^T (split-bf16): 12 tile-units over 8 waves
  int m16 = lane & 15, kg = lane >> 4;
#pragma unroll
  for (int uu = 0; uu < 2; ++uu) {
    int u = wv + uu * 8;
    if (u < 12) {
      int mt = u / 6, ntile = u % 6;
      floatx4 acc = {0.f, 0.f, 0.f, 0.f};
#pragma unroll
      for (int ks = 0; ks < 2; ++ks) {
        short8 ah = *(const short8*)&Qhi[(mt * 16 + m16) * 72 + ks * 32 + kg * 8];
        short8 al = *(const short8*)&Qlo[(mt * 16 + m16) * 72 + ks * 32 + kg * 8];
        short8 bh = *(const short8*)&Khi[(ntile * 16 + m16) * 72 + ks * 32 + kg * 8];
        short8 bl = *(const short8*)&Klo[(ntile * 16 + m16) * 72 + ks * 32 + kg * 8];
        acc = __builtin_amdgcn_mfma_f32_16x16x32_bf16(ah, bh, acc, 0, 0, 0);
        acc = __builtin_amdgcn_mfma_f32_16x16x32_bf16(al, bh, acc, 0, 0, 0);
        acc = __builtin_amdgcn_mfma_f32_16x16x32_bf16(ah, bl, acc, 0, 0, 0);
      }
#pragma unroll
      for (int r = 0; r < 4; ++r) Sf[(mt * 16 + kg * 4 + r) * 97 + ntile * 16 + m16] = acc[r];
    }
  }
  __syncthreads();

  // scores + softmax (sc<=0 analytically)
#pragma unroll
  for (int i = 0; i < 4; ++i) {
    int nl = wv * 4 + i;
    int r = nl + 1 + lane;
    float xy = Sf[nl * 97 + r];
    float x2 = x2s[nl], y2 = y2s[r];
    float bx = bxs[nl], gy = gys[r];

    float den = fmaf(c * c * x2, y2, fmaf(-2.f * c, xy, 1.f));
    den = fmaxf(den, EPSF);
    float rden = 1.f / den;
    float s2 = fmaxf(x2 - 2.f * xy + y2, 0.f);
    float z = sqrtf(c * s2 * rden);
    float omz2 = bx * gy * rden;
    float opz = 1.f + fminf(z, 1.f);
    float ratio = fminf(opz * opz / omz2, 1.9999999e7f);
    float sc = -gs * logf(ratio) * rsqc;

    float e = expf(sc);
    float se = wsum(e);
    Pb[nl * 104 + r] = f2bf(e / se);
  }
  __syncthreads();

  // PV: 8 tile-units, one per wave
  {
    int mt = wv >> 2, ntile = wv & 3;
    floatx4 acc = {0.f, 0.f, 0.f, 0.f};
#pragma unroll
    for (int ks = 0; ks < 3; ++ks) {
      short8 a = *(const short8*)&Pb[(mt * 16 + m16) * 104 + ks * 32 + kg * 8];
      short8 bb = *(const short8*)&Vt[(ntile * 16 + m16) * 104 + ks * 32 + kg * 8];
      acc = __builtin_amdgcn_mfma_f32_16x16x32_bf16(a, bb, acc, 0, 0, 0);
    }
#pragma unroll
    for (int r = 0; r < 4; ++r) {
      int qrow = mt * 16 + kg * 4 + r;
      int d = ntile * 16 + m16;
      attn_out[(size_t)(b * Nn + n0 + qrow) * DIMn + h * HDn + d] = f2bf(acc[r]);
    }
  }
}

// ---------------- the mega kernel: 7 phases, grid-wide sync between ----------------
__global__ __launch_bounds__(NTHR, 2) void mega(
    const float* x, const float* fcos, const float* fsin, const float* cvec,
    const float* Wq, const float* bq, const float* Wk, const float* bk,
    const float* Wv, const float* bv, const float* Wo, const float* bo,
    const float* W1, const float* b1, const float* W2, const float* b2,
    const float* ln1s, const float* ln1b, const float* ln2s, const float* ln2b,
    const float* geo, const float* hash,
    unsigned short* Wcat_hi, unsigned short* Wcat_lo, unsigned short* Wo_t,
    unsigned short* W1_t, unsigned short* W2_t,
    unsigned short* xn_hi, unsigned short* xn_lo, float* qkv,
    unsigned short* attnb, float* xout, unsigned short* hbuf,
    unsigned short* mid, float* bias_cat, float* out) {
  __shared__ __align__(16) char LU[70400];
  cg::grid_group grid = cg::this_grid();
  int tid = threadIdx.x, bid = blockIdx.x;

  // ---- phase 1: weight transposes + bias concat + LN1 ----
  if (bid == 0) {
    bias_cat[tid] = bq[tid];
    bias_cat[512 + tid] = bk[tid];
    bias_cat[1024 + tid] = bv[tid];
  }
  float* tb = (float*)LU;  // 32x33 tile
  for (int u = bid; u < 3072; u += NBLK) {
    const float* W;
    unsigned short* hi;
    unsigned short* lo = nullptr;
    int K, N, tix;
    if (u < 256)       { W = Wq; hi = Wcat_hi;              lo = Wcat_lo;              K = 512;  N = 512;  tix = u; }
    else if (u < 512)  { W = Wk; hi = Wcat_hi + 512 * 512;  lo = Wcat_lo + 512 * 512;  K = 512;  N = 512;  tix = u - 256; }
    else if (u < 768)  { W = Wv; hi = Wcat_hi + 1024 * 512; K = 512;  N = 512;  tix = u - 512; }
    else if (u < 1024) { W = Wo; hi = Wo_t;                 K = 512;  N = 512;  tix = u - 768; }
    else if (u < 2048) { W = W1; hi = W1_t;                 K = 512;  N = 2048; tix = u - 1024; }
    else               { W = W2; hi = W2_t;                 K = 2048; N = 512;  tix = u - 2048; }
    int ntn = N >> 5;
    int kt = tix / ntn, nt = tix - kt * ntn;
    int k0 = kt * 32, n0 = nt * 32;
    {
      int r = tid >> 4, cc = (tid & 15) << 1;
      float2 v = *(const float2*)&W[(size_t)(k0 + r) * N + n0 + cc];
      tb[r * 33 + cc] = v.x;
      tb[r * 33 + cc + 1] = v.y;
    }
    __syncthreads();
    for (int i = tid; i < 1024; i += NTHR) {
      int r = i >> 5, cc = i & 31;
      float v = tb[cc * 33 + r];
      unsigned short h = f2bf(v);
      size_t oi = (size_t)(n0 + r) * K + k0 + cc;
      hi[oi] = h;
      if (lo) lo[oi] = f2bf(v - bf2f(h));
    }
    __syncthreads();
  }
  {
    float* red = (float*)LU;
    for (int r0 = bid; r0 < Bn * Nn; r0 += NBLK)
      ln_row(x + (size_t)r0 * DIMn, ln1s, ln1b, xn_hi + (size_t)r0 * DIMn,
             xn_lo + (size_t)r0 * DIMn, red, tid);
  }
  grid.sync();

  // ---- phase 2: QKV GEMM (hybrid split) ----
  for (int u = bid; u < 768; u += NBLK)
    qkv_unit(xn_hi, xn_lo, Wcat_hi, Wcat_lo, bias_cat, qkv, u, tid, LU);
  grid.sync();

  // ---- phase 3: fused attention ----
  for (int u = bid; u < Bn * NHn * (Nn / 32); u += NBLK)
    attn_unit(qkv, fcos, fsin, cvec, geo, hash, attnb, u, tid, LU);
  grid.sync();

  // ---- phase 4: Wo + residual(x) -> xout ----
  {
    int u = bid;  // 256 units: 32 m-tiles x 8 n-tiles
    gemm_unit<1, 0>(attnb, Wo_t, bo, x, xout, (u >> 3) * 64, (u & 7) * 64, DIMn, 512, LU, tid);
  }
  grid.sync();

  // ---- phase 5: LN2 -> hbuf ----
  {
    float* red = (float*)LU;
    __syncthreads();  // LU handoff from gemm epilogue
    for (int r0 = bid; r0 < Bn * Nn; r0 += NBLK)
      ln_row(xout + (size_t)r0 * DIMn, ln2s, ln2b, hbuf + (size_t)r0 * DIMn, nullptr, red, tid);
  }
  grid.sync();

  // ---- phase 6: FFN1 + gelu -> mid ----
  for (int u = bid; u < 1024; u += NBLK)
    gemm_unit<2, 1>(hbuf, W1_t, b1, nullptr, mid, (u >> 5) * 64, (u & 31) * 64, 2048, 512, LU, tid);
  grid.sync();

  // ---- phase 7: FFN2 + residual(xout) -> out ----
  {
    int u = bid;  // 256 units: 32 m-tiles x 8 n-tiles
    gemm_unit<1, 0>(mid, W2_t, b2, xout, out, (u >> 3) * 64, (u & 7) * 64, DIMn, 2048, LU, tid);
  }
}

// ---------------- launcher ----------------
extern "C" void kernel_launch(void* const* d_in, const int* in_sizes, int n_in,
                              void* d_out, int out_size, void* d_ws, size_t ws_size,
                              hipStream_t stream) {
  const float* x    = (const float*)d_in[0];
  const float* fcos = (const float*)d_in[1];
  const float* fsin = (const float*)d_in[2];
  const float* cvec = (const float*)d_in[3];
  const float* Wq = (const float*)d_in[4];  const float* bq = (const float*)d_in[5];
  const float* Wk = (const float*)d_in[6];  const float* bk = (const float*)d_in[7];
  const float* Wv = (const float*)d_in[8];  const float* bv = (const float*)d_in[9];
  const float* Wo = (const float*)d_in[10]; const float* bo = (const float*)d_in[11];
  const float* W1 = (const float*)d_in[12]; const float* b1 = (const float*)d_in[13];
  const float* W2 = (const float*)d_in[14]; const float* b2 = (const float*)d_in[15];
  const float* ln1s = (const float*)d_in[16]; const float* ln1b = (const float*)d_in[17];
  const float* ln2s = (const float*)d_in[18]; const float* ln2b = (const float*)d_in[19];
  const float* geo  = (const float*)d_in[20]; const float* hash = (const float*)d_in[21];
  float* out = (float*)d_out;
  char* base = (char*)d_ws;

  unsigned short* Wcat_hi = (unsigned short*)(base + 0);
  unsigned short* Wcat_lo = (unsigned short*)(base + 1572864);
  unsigned short* Wo_t    = (unsigned short*)(base + 3145728);
  unsigned short* W1_t    = (unsigned short*)(base + 3670016);
  unsigned short* W2_t    = (unsigned short*)(base + 5767168);
  unsigned short* xn_hi   = (unsigned short*)(base + 7864320);
  unsigned short* xn_lo   = (unsigned short*)(base + 9961472);
  float*          qkv     = (float*)(base + 12058624);
  unsigned short* attnb   = (unsigned short*)(base + 7864320);   // reuse xn_hi
  float*          xout    = (float*)(base + 9961472);            // reuse xn_lo
  unsigned short* hbuf    = (unsigned short*)(base + 14155776);
  unsigned short* mid     = (unsigned short*)(base + 16252928);
  float*          bias_cat= (float*)(base + 24641536);

  void* args[] = {
    (void*)&x, (void*)&fcos, (void*)&fsin, (void*)&cvec,
    (void*)&Wq, (void*)&bq, (void*)&Wk, (void*)&bk,
    (void*)&Wv, (void*)&bv, (void*)&Wo, (void*)&bo,
    (void*)&W1, (void*)&b1, (void*)&W2, (void*)&b2,
    (void*)&ln1s, (void*)&ln1b, (void*)&ln2s, (void*)&ln2b,
    (void*)&geo, (void*)&hash,
    (void*)&Wcat_hi, (void*)&Wcat_lo, (void*)&Wo_t, (void*)&W1_t, (void*)&W2_t,
    (void*)&xn_hi, (void*)&xn_lo, (void*)&qkv, (void*)&attnb, (void*)&xout,
    (void*)&hbuf, (void*)&mid, (void*)&bias_cat, (void*)&out
  };
  hipLaunchCooperativeKernel(reinterpret_cast<void*>(mega), dim3(NBLK), dim3(NTHR),
                             args, 0, stream);
}

// Round 8
// 179.919 us; speedup vs baseline: 2.4169x; 2.4169x over previous
//
#include <hip/hip_runtime.h>
#include <math.h>
#include <stdint.h>

#define Bn   2
#define Nn   1024
#define DIMn 512
#define NHn  8
#define HDn  64
#define QKVS 1536
#define EPSF 1e-7f

typedef __attribute__((ext_vector_type(8))) short short8;
typedef __attribute__((ext_vector_type(4))) float floatx4;
typedef __attribute__((ext_vector_type(4))) float fx4;
typedef __attribute__((ext_vector_type(4))) unsigned short usx4;

// ---------------- bf16 helpers (RNE) ----------------
__device__ __forceinline__ unsigned short f2bf(float f) {
  union { float f; uint32_t u; } v; v.f = f;
  uint32_t u = v.u;
  return (unsigned short)((u + 0x7FFFu + ((u >> 16) & 1u)) >> 16);
}
__device__ __forceinline__ float bf2f(unsigned short h) {
  union { uint32_t u; float f; } v; v.u = ((uint32_t)h) << 16;
  return v.f;
}

// ---------------- wave helpers (wave64) ----------------
__device__ __forceinline__ float wsum(float v) {
#pragma unroll
  for (int m = 32; m >= 1; m >>= 1) v += __shfl_xor(v, m, 64);
  return v;
}

__device__ __forceinline__ float gelu_tanh(float x) {
  const float k0 = 0.7978845608028654f;  // sqrt(2/pi)
  float x3 = x * x * x;
  return 0.5f * x * (1.f + tanhf(k0 * (x + 0.044715f * x3)));
}

// ---------------- async global->LDS 16B ----------------
__device__ __forceinline__ void glds16(const unsigned short* g, unsigned short* l) {
  __builtin_amdgcn_global_load_lds((const __attribute__((address_space(1))) void*)g,
                                   (__attribute__((address_space(3))) void*)l, 16, 0, 0);
}

// ---------------- merged: weight transpose/convert + bias concat + LN1 ----------------
__global__ __launch_bounds__(256) void prep_kernel(
    const float* __restrict__ Wq, const float* __restrict__ Wk,
    const float* __restrict__ Wv, const float* __restrict__ Wo,
    const float* __restrict__ W1, const float* __restrict__ W2,
    unsigned short* __restrict__ Wcat_hi, unsigned short* __restrict__ Wcat_lo,
    unsigned short* __restrict__ Wo_t, unsigned short* __restrict__ W1_t,
    unsigned short* __restrict__ W2_t,
    const float* __restrict__ bq, const float* __restrict__ bk,
    const float* __restrict__ bv, float* __restrict__ bias_cat,
    const float* __restrict__ x, const float* __restrict__ ln1s,
    const float* __restrict__ ln1b,
    unsigned short* __restrict__ xn_hi, unsigned short* __restrict__ xn_lo) {
  __shared__ float t[32][33];
  __shared__ float red[2][4];
  int bid = blockIdx.x;
  int tid = threadIdx.x;
  if (bid == 3072) {  // bias concat
    for (int i = tid; i < 512; i += 256) {
      bias_cat[i] = bq[i];
      bias_cat[512 + i] = bk[i];
      bias_cat[1024 + i] = bv[i];
    }
    return;
  }
  if (bid > 3072) {  // LN1 row
    int row = bid - 3073;
    const float* xr = x + (size_t)row * DIMn;
    float2 xv = *(const float2*)(xr + tid * 2);
    float s  = xv.x + xv.y;
    float s2 = xv.x * xv.x + xv.y * xv.y;
    s = wsum(s); s2 = wsum(s2);
    int wv = tid >> 6;
    if ((tid & 63) == 0) { red[0][wv] = s; red[1][wv] = s2; }
    __syncthreads();
    s  = red[0][0] + red[0][1] + red[0][2] + red[0][3];
    s2 = red[1][0] + red[1][1] + red[1][2] + red[1][3];
    float mean = s * (1.f / DIMn);
    float var  = s2 * (1.f / DIMn) - mean * mean;
    float rstd = rsqrtf(var + 1e-6f);
    int d = tid * 2;
    float2 gv = *(const float2*)(ln1s + d);
    float2 bv2 = *(const float2*)(ln1b + d);
    float o0 = (xv.x - mean) * rstd * gv.x + bv2.x;
    float o1 = (xv.y - mean) * rstd * gv.y + bv2.y;
    size_t idx = (size_t)row * DIMn + d;
    unsigned short h0 = f2bf(o0), h1 = f2bf(o1);
    ushort2 hv; hv.x = h0; hv.y = h1;
    *(ushort2*)(xn_hi + idx) = hv;
    ushort2 lv; lv.x = f2bf(o0 - bf2f(h0)); lv.y = f2bf(o1 - bf2f(h1));
    *(ushort2*)(xn_lo + idx) = lv;
    return;
  }
  // weight transpose tile
  const float* W;
  unsigned short* hi;
  unsigned short* lo = nullptr;
  int K, N, tix;
  if (bid < 256)       { W = Wq; hi = Wcat_hi;               lo = Wcat_lo;               K = 512;  N = 512;  tix = bid; }
  else if (bid < 512)  { W = Wk; hi = Wcat_hi + 512 * 512;   lo = Wcat_lo + 512 * 512;   K = 512;  N = 512;  tix = bid - 256; }
  else if (bid < 768)  { W = Wv; hi = Wcat_hi + 1024 * 512;  K = 512;  N = 512;  tix = bid - 512; }
  else if (bid < 1024) { W = Wo; hi = Wo_t;                  K = 512;  N = 512;  tix = bid - 768; }
  else if (bid < 2048) { W = W1; hi = W1_t;                  K = 512;  N = 2048; tix = bid - 1024; }
  else                 { W = W2; hi = W2_t;                  K = 2048; N = 512;  tix = bid - 2048; }
  int ntn = N >> 5;
  int kt = tix / ntn, nt = tix - kt * ntn;
  int k0 = kt * 32, n0 = nt * 32;
  {
    // vectorized tile load: one float4 per thread covers 32x32
    int r = tid >> 3, c = (tid & 7) << 2;
    fx4 v = *(const fx4*)&W[(size_t)(k0 + r) * N + n0 + c];
    t[r][c] = v.x; t[r][c + 1] = v.y; t[r][c + 2] = v.z; t[r][c + 3] = v.w;
  }
  __syncthreads();
  for (int i = tid; i < 1024; i += 256) {
    int r = i >> 5, c = i & 31;
    float v = t[c][r];
    unsigned short h = f2bf(v);
    size_t oi = (size_t)(n0 + r) * K + k0 + c;
    hi[oi] = h;
    if (lo) lo[oi] = f2bf(v - bf2f(h));
  }
}

// ---------------- LayerNorm -> bf16 (plain) ----------------
__global__ __launch_bounds__(256) void ln_kernel(const float* __restrict__ x,
                                                 const float* __restrict__ g,
                                                 const float* __restrict__ be,
                                                 unsigned short* __restrict__ yhi) {
  __shared__ float red[2][4];
  int row = blockIdx.x;
  int tid = threadIdx.x;
  const float* xr = x + (size_t)row * DIMn;
  float2 xv = *(const float2*)(xr + tid * 2);
  float s  = xv.x + xv.y;
  float s2 = xv.x * xv.x + xv.y * xv.y;
  s = wsum(s); s2 = wsum(s2);
  int wv = tid >> 6;
  if ((tid & 63) == 0) { red[0][wv] = s; red[1][wv] = s2; }
  __syncthreads();
  s  = red[0][0] + red[0][1] + red[0][2] + red[0][3];
  s2 = red[1][0] + red[1][1] + red[1][2] + red[1][3];
  float mean = s * (1.f / DIMn);
  float var  = s2 * (1.f / DIMn) - mean * mean;
  float rstd = rsqrtf(var + 1e-6f);
  int d = tid * 2;
  float2 gv = *(const float2*)(g + d);
  float2 bv = *(const float2*)(be + d);
  float o0 = (xv.x - mean) * rstd * gv.x + bv.x;
  float o1 = (xv.y - mean) * rstd * gv.y + bv.y;
  size_t idx = (size_t)row * DIMn + d;
  ushort2 hv; hv.x = f2bf(o0); hv.y = f2bf(o1);
  *(ushort2*)(yhi + idx) = hv;
}

// ---------------- plain bf16 MFMA GEMM, double-buffered, 1 barrier/K-tile --------------
// LDS bank-conflict fix: linear LDS dest (glds16 constraint) + XOR-swizzled global
// SOURCE chunk + matching XOR on ds_read chunk (rule #21 / m173 pattern).
// BKT=64: chunk = 16B; row stride 128B put 16 lanes on one bank-group (16-way).
// src/read chunk ci ^ (row&7) -> 8 slots x 2 lanes = 2-way (free, m136).
// EPI: 0=bias, 1=bias+res, 2=bias+gelu.  LDS-bounce coalesced epilogue.
template <int BM, int BN, int BKT, int EPI, int OUTBF16>
__global__ __launch_bounds__(256) void gemm_db(
    const unsigned short* __restrict__ Ahi,
    const unsigned short* __restrict__ Bhi,
    const float* __restrict__ bias, const float* __restrict__ res,
    void* __restrict__ outp, int M, int N, int K) {
  constexpr int FI = BM / 32, FJ = BN / 32;
  constexpr int AE = BM * BKT, BE = BN * BKT;
  constexpr int CPR = BKT / 8;   // 16B chunks per row (8 for BKT=64)
  constexpr int ACH = BM * CPR, BCH = BN * CPR;
  constexpr int CST = BN + 4;
  constexpr int STG = AE + BE;
  constexpr int SMEM_EPI = BM * CST * 2;          // shorts
  constexpr int SMEM_N = (2 * STG > SMEM_EPI) ? 2 * STG : SMEM_EPI;
  __shared__ __align__(16) unsigned short smem[SMEM_N];

  int tid = threadIdx.x;
  int lane = tid & 63;
  int wid = tid >> 6;
  int wm = (wid >> 1) * (BM / 2), wn = (wid & 1) * (BN / 2);
  int bm = blockIdx.y * BM, bn = blockIdx.x * BN;
  int m16 = lane & 15, kg = lane >> 4;

  floatx4 acc[FI][FJ];
#pragma unroll
  for (int i = 0; i < FI; ++i)
#pragma unroll
    for (int j = 0; j < FJ; ++j) { floatx4 z = {0.f, 0.f, 0.f, 0.f}; acc[i][j] = z; }

  const unsigned short* aph = Ahi + (size_t)bm * K;
  const unsigned short* bph = Bhi + (size_t)bn * K;

  auto stage = [&](int k0, unsigned short* As, unsigned short* Bs) {
    for (int c = tid; c < ACH; c += 256) {
      int row = c / CPR, ci = c % CPR;
      int sci = ci ^ (row & 7);
      glds16(aph + (size_t)row * K + k0 + sci * 8, As + c * 8);
    }
    for (int c = tid; c < BCH; c += 256) {
      int row = c / CPR, ci = c % CPR;
      int sci = ci ^ (row & 7);
      glds16(bph + (size_t)row * K + k0 + sci * 8, Bs + c * 8);
    }
  };

  const int NT = K / BKT;
  stage(0, smem, smem + AE);
  __syncthreads();
  int cur = 0;
  for (int t = 0; t < NT; ++t) {
    unsigned short* As = smem + cur * STG;
    unsigned short* Bs = As + AE;
    int nxt = cur ^ 1;
    if (t + 1 < NT) stage((t + 1) * BKT, smem + nxt * STG, smem + nxt * STG + AE);
#pragma unroll
    for (int ks = 0; ks < BKT / 32; ++ks) {
      short8 ah[FI], bh[FJ];
#pragma unroll
      for (int i = 0; i < FI; ++i) {
        int r = wm + i * 16 + m16;
        ah[i] = *(const short8*)&As[r * BKT + (((ks * 4 + kg) ^ (r & 7)) << 3)];
      }
#pragma unroll
      for (int j = 0; j < FJ; ++j) {
        int r = wn + j * 16 + m16;
        bh[j] = *(const short8*)&Bs[r * BKT + (((ks * 4 + kg) ^ (r & 7)) << 3)];
      }
#pragma unroll
      for (int i = 0; i < FI; ++i)
#pragma unroll
        for (int j = 0; j < FJ; ++j)
          acc[i][j] = __builtin_amdgcn_mfma_f32_16x16x32_bf16(ah[i], bh[j], acc[i][j], 0, 0, 0);
    }
    __syncthreads();   // drains vmcnt (next tile landed) + protects buf reuse
    cur = nxt;
  }

  // --- LDS-bounce epilogue ---
  float* Cs = (float*)smem;
#pragma unroll
  for (int i = 0; i < FI; ++i)
#pragma unroll
    for (int j = 0; j < FJ; ++j)
#pragma unroll
      for (int r = 0; r < 4; ++r)
        Cs[(wm + i * 16 + kg * 4 + r) * CST + wn + j * 16 + m16] = acc[i][j][r];
  __syncthreads();
  constexpr int TOT = BM * BN / 4;
  for (int t = tid; t < TOT; t += 256) {
    int row = (t << 2) / BN;
    int col = (t << 2) & (BN - 1);
    fx4 v = *(const fx4*)&Cs[row * CST + col];
    fx4 bs = *(const fx4*)&bias[bn + col];
    v = v + bs;
    size_t gidx = (size_t)(bm + row) * N + bn + col;
    if constexpr (EPI == 1) {
      fx4 rr = *(const fx4*)&res[gidx];
      v = v + rr;
    }
    if constexpr (EPI == 2) {
      v.x = gelu_tanh(v.x); v.y = gelu_tanh(v.y);
      v.z = gelu_tanh(v.z); v.w = gelu_tanh(v.w);
    }
    if constexpr (OUTBF16) {
      usx4 h;
      h.x = f2bf(v.x); h.y = f2bf(v.y); h.z = f2bf(v.z); h.w = f2bf(v.w);
      *(usx4*)((unsigned short*)outp + gidx) = h;
    } else {
      *(fx4*)((float*)outp + gidx) = v;
    }
  }
}

// ---------------- QKV GEMM: hybrid split-bf16, double-buffered, 1 barrier/K-tile -------
// BKT=32 (4 chunks/row).  Bank fix: swizzle s(row) = (row>>1)&3 (uses the row-parity
// bank bit): 16 lanes spread over 8 bank-groups = 2-way (free).  Source + read XOR'd.
__global__ __launch_bounds__(256) void qkv_gemm(
    const unsigned short* __restrict__ Ahi, const unsigned short* __restrict__ Alo,
    const unsigned short* __restrict__ Bhi, const unsigned short* __restrict__ Blo,
    const float* __restrict__ bias, float* __restrict__ outp) {
  constexpr int BM = 64, BN = 64, BKT = 32, K = 512, N = QKVS;
  constexpr int FI = 2, FJ = 2;
  constexpr int AE = BM * BKT, BE = BN * BKT;   // 2048 shorts each
  constexpr int CST = BN + 4;
  constexpr int STG = 2 * (AE + BE);            // hi+lo for A and B = 8192 shorts
  constexpr int SMEM_EPI = BM * CST * 2;
  constexpr int SMEM_N = (2 * STG > SMEM_EPI) ? 2 * STG : SMEM_EPI;
  __shared__ __align__(16) unsigned short smem[SMEM_N];

  int tid = threadIdx.x;
  int lane = tid & 63;
  int wid = tid >> 6;
  int wm = (wid >> 1) * 32, wn = (wid & 1) * 32;
  int bm = blockIdx.y * BM, bn = blockIdx.x * BN;
  int m16 = lane & 15, kg = lane >> 4;
  bool dos = bn < 1024;  // split precision for Q,K only

  floatx4 acc[FI][FJ];
#pragma unroll
  for (int i = 0; i < FI; ++i)
#pragma unroll
    for (int j = 0; j < FJ; ++j) { floatx4 z = {0.f, 0.f, 0.f, 0.f}; acc[i][j] = z; }

  const unsigned short* aph = Ahi + (size_t)bm * K;
  const unsigned short* bph = Bhi + (size_t)bn * K;
  const unsigned short* apl = Alo + (size_t)bm * K;
  const unsigned short* bpl = Blo + (size_t)bn * K;

  // buffer layout per stage: [AsHi AE][AsLo AE][BsHi BE][BsLo BE]
  auto stage = [&](int k0, unsigned short* buf) {
    {
      int c = tid;  // 256 A-chunks
      int row = c >> 2, ci = c & 3;
      int sci = ci ^ ((row >> 1) & 3);
      glds16(aph + (size_t)row * K + k0 + sci * 8, buf + c * 8);
      if (dos) glds16(apl + (size_t)row * K + k0 + sci * 8, buf + AE + c * 8);
    }
    {
      int c = tid;  // 256 B-chunks
      int row = c >> 2, ci = c & 3;
      int sci = ci ^ ((row >> 1) & 3);
      glds16(bph + (size_t)row * K + k0 + sci * 8, buf + 2 * AE + c * 8);
      if (dos) glds16(bpl + (size_t)row * K + k0 + sci * 8, buf + 2 * AE + BE + c * 8);
    }
  };

  const int NT = K / BKT;  // 16
  stage(0, smem);
  __syncthreads();
  int cur = 0;
  for (int t = 0; t < NT; ++t) {
    unsigned short* buf = smem + cur * STG;
    unsigned short* AsHi = buf;
    unsigned short* AsLo = buf + AE;
    unsigned short* BsHi = buf + 2 * AE;
    unsigned short* BsLo = buf + 2 * AE + BE;
    int nxt = cur ^ 1;
    if (t + 1 < NT) stage((t + 1) * BKT, smem + nxt * STG);

    short8 ah[FI], bh[FJ], al[FI], bl[FJ];
#pragma unroll
    for (int i = 0; i < FI; ++i) {
      int r = wm + i * 16 + m16;
      int off = r * BKT + ((kg ^ ((r >> 1) & 3)) << 3);
      ah[i] = *(const short8*)&AsHi[off];
      if (dos) al[i] = *(const short8*)&AsLo[off];
    }
#pragma unroll
    for (int j = 0; j < FJ; ++j) {
      int r = wn + j * 16 + m16;
      int off = r * BKT + ((kg ^ ((r >> 1) & 3)) << 3);
      bh[j] = *(const short8*)&BsHi[off];
      if (dos) bl[j] = *(const short8*)&BsLo[off];
    }
#pragma unroll
    for (int i = 0; i < FI; ++i)
#pragma unroll
      for (int j = 0; j < FJ; ++j) {
        acc[i][j] = __builtin_amdgcn_mfma_f32_16x16x32_bf16(ah[i], bh[j], acc[i][j], 0, 0, 0);
        if (dos) {
          acc[i][j] = __builtin_amdgcn_mfma_f32_16x16x32_bf16(al[i], bh[j], acc[i][j], 0, 0, 0);
          acc[i][j] = __builtin_amdgcn_mfma_f32_16x16x32_bf16(ah[i], bl[j], acc[i][j], 0, 0, 0);
        }
      }
    __syncthreads();
    cur = nxt;
  }

  // --- LDS-bounce epilogue (f32 out + bias) ---
  float* Cs = (float*)smem;
#pragma unroll
  for (int i = 0; i < FI; ++i)
#pragma unroll
    for (int j = 0; j < FJ; ++j)
#pragma unroll
      for (int r = 0; r < 4; ++r)
        Cs[(wm + i * 16 + kg * 4 + r) * CST + wn + j * 16 + m16] = acc[i][j][r];
  __syncthreads();
  constexpr int TOT = BM * BN / 4;
  for (int t = tid; t < TOT; t += 256) {
    int row = (t << 2) / BN;
    int col = (t << 2) & (BN - 1);
    fx4 v = *(const fx4*)&Cs[row * CST + col];
    fx4 bs = *(const fx4*)&bias[bn + col];
    v = v + bs;
    size_t gidx = (size_t)(bm + row) * N + bn + col;
    *(fx4*)(outp + gidx) = v;
  }
}

// ---------------- fused hash+RoPE+expmap0 + windowed Poincare attention ----------------
// 512 threads (8 waves) per block; block = (b, h, 32-query tile).
__global__ __launch_bounds__(512) void attn_fused(const float* __restrict__ qkv,
                                                  const float* __restrict__ fcos,
                                                  const float* __restrict__ fsin,
                                                  const float* __restrict__ cvec,
                                                  const float* __restrict__ geo,
                                                  const float* __restrict__ hash,
                                                  unsigned short* __restrict__ attn_out) {
  __shared__ unsigned short Qhi[32][72], Qlo[32][72];   // pad 72: 2-way aliasing only
  __shared__ unsigned short Khi[96][72], Klo[96][72];
  __shared__ unsigned short Vt[64][104];                // V^T [d][key], bf16
  __shared__ unsigned short Pb[32][104];                // softmax weights [query][key]
  __shared__ float Sf[32][97];
  __shared__ float x2s[32], bxs[32], y2s[96], gys[96];

  int tid = threadIdx.x, lane = tid & 63, wv = tid >> 6;  // wv in [0,8)
  int bid = blockIdx.x;  // 512 = B*NH*(N/32)
  int nt = bid & 31, h = (bid >> 5) & 7, b = bid >> 8;
  int n0 = nt * 32;
  float c = cvec[b];
  float sqc = sqrtf(c);
  float rsqc = 1.f / sqc;
  float gs = geo[h];
  int dr = lane & 31;
  bool hih = lane >= 32;
  const float LOG9 = 2.1972245773362196f;
  float hofr = hash[h * HDn + dr] * LOG9;
  float hofi = hash[h * HDn + dr + 32] * LOG9;

  for (int i = tid; i < 32 * 52; i += 512) ((uint32_t*)Pb)[i] = 0u;

  // --- stage Q (4 rows/wave) ---
#pragma unroll
  for (int i = 0; i < 4; ++i) {
    int q = wv * 4 + i;
    int n = n0 + q;
    size_t bas = (size_t)(b * Nn + n) * QKVS + h * HDn;
    float qr = qkv[bas + dr] + hofr;
    float qi = qkv[bas + dr + 32] + hofi;
    float cs = fcos[n * 32 + dr], sn = fsin[n * 32 + dr];
    float qv = hih ? (qr * sn + qi * cs) : (qr * cs - qi * sn);
    float nq = sqrtf(wsum(qv * qv));
    float sq = fmaxf(nq, EPSF);
    float t = sqc * sq;
    float em = expf(-2.f * t);
    float opem = 1.f + em;
    float mag = ((1.f - em) / opem) * rsqc;
    float sech2 = 4.f * em / (opem * opem);
    float oq = (nq < EPSF) ? 0.f : mag * (qv / sq);
    unsigned short hh = f2bf(oq);
    Qhi[q][lane] = hh;
    Qlo[q][lane] = f2bf(oq - bf2f(hh));
    if (lane == 0) {
      x2s[q] = (nq < EPSF) ? 0.f : mag * mag;
      bxs[q] = (nq < EPSF) ? 1.f : sech2;
    }
  }
  // --- stage K (12 rows/wave) + V^T ---
#pragma unroll 4
  for (int i = 0; i < 12; ++i) {
    int r = wv * 12 + i;
    int gi = n0 - 64 + r;
    float ok = 0.f, vf = 0.f, y2 = 0.f, gy = 1.f;
    if (gi >= 0) {
      size_t bas = (size_t)(b * Nn + gi) * QKVS + h * HDn;
      float kr = qkv[bas + 512 + dr];
      float ki = qkv[bas + 512 + dr + 32];
      vf = qkv[bas + 1024 + lane];
      float cs = fcos[gi * 32 + dr], sn = fsin[gi * 32 + dr];
      float kv = hih ? (kr * sn + ki * cs) : (kr * cs - ki * sn);
      float nk = sqrtf(wsum(kv * kv));
      float sk = fmaxf(nk, EPSF);
      float t = sqc * sk;
      float em = expf(-2.f * t);
      float opem = 1.f + em;
      float mag = ((1.f - em) / opem) * rsqc;
      float sech2 = 4.f * em / (opem * opem);
      ok = (nk < EPSF) ? 0.f : mag * (kv / sk);
      y2 = (nk < EPSF) ? 0.f : mag * mag;
      gy = (nk < EPSF) ? 1.f : sech2;
    }
    unsigned short hh = f2bf(ok);
    Khi[r][lane] = hh;
    Klo[r][lane] = f2bf(ok - bf2f(hh));
    Vt[lane][r] = f2bf(vf);
    if (lane == 0) { y2s[r] = y2; gys[r] = gy; }
  }
  __syncthreads();

  // --- S = Q K^T via split-bf16 MFMA: 12 tile-units (2 mt x 6 nt) over 8 waves ---
  int m16 = lane & 15, kg = lane >> 4;
#pragma unroll
  for (int uu = 0; uu < 2; ++uu) {
    int u = wv + uu * 8;
    if (u < 12) {
      int mt = u / 6, ntile = u % 6;
      floatx4 acc = {0.f, 0.f, 0.f, 0.f};
#pragma unroll
      for (int ks = 0; ks < 2; ++ks) {
        short8 ah = *(const short8*)&Qhi[mt * 16 + m16][ks * 32 + kg * 8];
        short8 al = *(const short8*)&Qlo[mt * 16 + m16][ks * 32 + kg * 8];
        short8 bh = *(const short8*)&Khi[ntile * 16 + m16][ks * 32 + kg * 8];
        short8 bl = *(const short8*)&Klo[ntile * 16 + m16][ks * 32 + kg * 8];
        acc = __builtin_amdgcn_mfma_f32_16x16x32_bf16(ah, bh, acc, 0, 0, 0);
        acc = __builtin_amdgcn_mfma_f32_16x16x32_bf16(al, bh, acc, 0, 0, 0);
        acc = __builtin_amdgcn_mfma_f32_16x16x32_bf16(ah, bl, acc, 0, 0, 0);
      }
#pragma unroll
      for (int r = 0; r < 4; ++r) Sf[mt * 16 + kg * 4 + r][ntile * 16 + m16] = acc[r];
    }
  }
  __syncthreads();

  // --- scores + softmax (sc<=0 analytically; no max-subtraction needed) ---
#pragma unroll
  for (int i = 0; i < 4; ++i) {
    int nl = wv * 4 + i;
    int r = nl + 1 + lane;
    float xy = Sf[nl][r];
    float x2 = x2s[nl], y2 = y2s[r];
    float bx = bxs[nl], gy = gys[r];

    float den = fmaf(c * c * x2, y2, fmaf(-2.f * c, xy, 1.f));
    den = fmaxf(den, EPSF);
    float rden = 1.f / den;
    float s2 = fmaxf(x2 - 2.f * xy + y2, 0.f);
    float z = sqrtf(c * s2 * rden);
    float omz2 = bx * gy * rden;
    float opz = 1.f + fminf(z, 1.f);
    float ratio = fminf(opz * opz / omz2, 1.9999999e7f);
    float sc = -gs * logf(ratio) * rsqc;

    float e = expf(sc);
    float se = wsum(e);
    Pb[nl][r] = f2bf(e / se);
  }
  __syncthreads();

  // --- PV via MFMA: 8 tile-units (2 mt x 4 nt), one per wave ---
  {
    int mt = wv >> 2, ntile = wv & 3;
    floatx4 acc = {0.f, 0.f, 0.f, 0.f};
#pragma unroll
    for (int ks = 0; ks < 3; ++ks) {
      short8 a = *(const short8*)&Pb[mt * 16 + m16][ks * 32 + kg * 8];
      short8 bb = *(const short8*)&Vt[ntile * 16 + m16][ks * 32 + kg * 8];
      acc = __builtin_amdgcn_mfma_f32_16x16x32_bf16(a, bb, acc, 0, 0, 0);
    }
#pragma unroll
    for (int r = 0; r < 4; ++r) {
      int qrow = mt * 16 + kg * 4 + r;
      int d = ntile * 16 + m16;
      attn_out[(size_t)(b * Nn + n0 + qrow) * DIMn + h * HDn + d] = f2bf(acc[r]);
    }
  }
}

// ---------------- launcher ----------------
extern "C" void kernel_launch(void* const* d_in, const int* in_sizes, int n_in,
                              void* d_out, int out_size, void* d_ws, size_t ws_size,
                              hipStream_t stream) {
  const float* x    = (const float*)d_in[0];
  const float* fcos = (const float*)d_in[1];
  const float* fsin = (const float*)d_in[2];
  const float* cvec = (const float*)d_in[3];
  const float* Wq = (const float*)d_in[4];  const float* bq = (const float*)d_in[5];
  const float* Wk = (const float*)d_in[6];  const float* bk = (const float*)d_in[7];
  const float* Wv = (const float*)d_in[8];  const float* bv = (const float*)d_in[9];
  const float* Wo = (const float*)d_in[10]; const float* bo = (const float*)d_in[11];
  const float* W1 = (const float*)d_in[12]; const float* b1 = (const float*)d_in[13];
  const float* W2 = (const float*)d_in[14]; const float* b2 = (const float*)d_in[15];
  const float* ln1s = (const float*)d_in[16]; const float* ln1b = (const float*)d_in[17];
  const float* ln2s = (const float*)d_in[18]; const float* ln2b = (const float*)d_in[19];
  const float* geo  = (const float*)d_in[20]; const float* hash = (const float*)d_in[21];
  float* out = (float*)d_out;
  char* base = (char*)d_ws;

  unsigned short* Wcat_hi = (unsigned short*)(base + 0);         // 1536x512 bf16
  unsigned short* Wcat_lo = (unsigned short*)(base + 1572864);
  unsigned short* Wo_t    = (unsigned short*)(base + 3145728);   // 512x512
  unsigned short* W1_t    = (unsigned short*)(base + 3670016);   // 2048x512
  unsigned short* W2_t    = (unsigned short*)(base + 5767168);   // 512x2048
  unsigned short* xn_hi   = (unsigned short*)(base + 7864320);   // 2048x512
  unsigned short* xn_lo   = (unsigned short*)(base + 9961472);
  float*          qkv     = (float*)(base + 12058624);           // 2048x1536 f32
  unsigned short* attnb   = (unsigned short*)(base + 7864320);   // reuse xn_hi
  float*          xout    = (float*)(base + 9961472);            // 2048x512 f32 (reuse)
  unsigned short* hbuf    = (unsigned short*)(base + 14155776);  // 2048x512
  unsigned short* mid     = (unsigned short*)(base + 16252928);  // 2048x2048
  float*          bias_cat= (float*)(base + 24641536);           // 1536 f32

  const int M = Bn * Nn;  // 2048

  // 1) weight conversion + bias concat + LN1 (merged)
  prep_kernel<<<3073 + M, 256, 0, stream>>>(Wq, Wk, Wv, Wo, W1, W2, Wcat_hi, Wcat_lo,
                                            Wo_t, W1_t, W2_t, bq, bk, bv, bias_cat,
                                            x, ln1s, ln1b, xn_hi, xn_lo);
  // 2) QKV GEMM, hybrid split, 64x64 BK=32 dbuf + bank-conflict swizzle
  qkv_gemm<<<dim3(QKVS / 64, M / 64), 256, 0, stream>>>(
      xn_hi, xn_lo, Wcat_hi, Wcat_lo, bias_cat, qkv);
  // 3) fused rope + windowed Poincare attention (unchanged) -> attnb bf16
  attn_fused<<<Bn * NHn * (Nn / 32), 512, 0, stream>>>(qkv, fcos, fsin, cvec, geo, hash, attnb);
  // 4) Wo + residual(x) -> xout f32; 32x32 dbuf + swizzle
  gemm_db<32, 32, 64, 1, 0><<<dim3(DIMn / 32, M / 32), 256, 0, stream>>>(
      attnb, Wo_t, bo, x, xout, M, DIMn, 512);
  // 5) LN2 -> hbuf bf16
  ln_kernel<<<M, 256, 0, stream>>>(xout, ln2s, ln2b, hbuf);
  // 6) FFN1 + gelu -> mid bf16; 64x64 dbuf + swizzle
  gemm_db<64, 64, 64, 2, 1><<<dim3(2048 / 64, M / 64), 256, 0, stream>>>(
      hbuf, W1_t, b1, nullptr, mid, M, 2048, 512);
  // 7) FFN2 + residual(xout) -> out f32; 32x32 dbuf + swizzle
  gemm_db<32, 32, 64, 1, 0><<<dim3(DIMn / 32, M / 32), 256, 0, stream>>>(
      mid, W2_t, b2, xout, out, M, DIMn, 2048);
}

// Round 9
// 178.993 us; speedup vs baseline: 2.4294x; 1.0052x over previous
//
#include <hip/hip_runtime.h>
#include <math.h>
#include <stdint.h>

#define Bn   2
#define Nn   1024
#define DIMn 512
#define NHn  8
#define HDn  64
#define QKVS 1536
#define EPSF 1e-7f

typedef __attribute__((ext_vector_type(8))) short short8;
typedef __attribute__((ext_vector_type(4))) float floatx4;
typedef __attribute__((ext_vector_type(4))) float fx4;
typedef __attribute__((ext_vector_type(4))) unsigned short usx4;

// ---------------- bf16 helpers (RNE) ----------------
__device__ __forceinline__ unsigned short f2bf(float f) {
  union { float f; uint32_t u; } v; v.f = f;
  uint32_t u = v.u;
  return (unsigned short)((u + 0x7FFFu + ((u >> 16) & 1u)) >> 16);
}
__device__ __forceinline__ float bf2f(unsigned short h) {
  union { uint32_t u; float f; } v; v.u = ((uint32_t)h) << 16;
  return v.f;
}

// ---------------- wave helpers (wave64) ----------------
__device__ __forceinline__ float wsum(float v) {
#pragma unroll
  for (int m = 32; m >= 1; m >>= 1) v += __shfl_xor(v, m, 64);
  return v;
}

__device__ __forceinline__ float gelu_tanh(float x) {
  const float k0 = 0.7978845608028654f;  // sqrt(2/pi)
  float x3 = x * x * x;
  return 0.5f * x * (1.f + tanhf(k0 * (x + 0.044715f * x3)));
}

// ---------------- async global->LDS 16B ----------------
__device__ __forceinline__ void glds16(const unsigned short* g, unsigned short* l) {
  __builtin_amdgcn_global_load_lds((const __attribute__((address_space(1))) void*)g,
                                   (__attribute__((address_space(3))) void*)l, 16, 0, 0);
}

// ---------------- 64x64 transpose+convert unit (256 threads, float4/ushort4) ----------
// W is K x N row-major; writes hi[n][k] (+ optional lo residual).
__device__ void tr64(const float* __restrict__ W, unsigned short* __restrict__ hi,
                     unsigned short* __restrict__ lo, int K, int N, int tix, int tid,
                     float* tile /* 64*65 floats */) {
  int ntn = N >> 6;
  int kt = tix / ntn, nt = tix - kt * ntn;
  int k0 = kt * 64, n0 = nt * 64;
  int rb = tid >> 4, c4 = (tid & 15) * 4;
#pragma unroll
  for (int rr = 0; rr < 4; ++rr) {
    int r = rr * 16 + rb;
    fx4 v = *(const fx4*)&W[(size_t)(k0 + r) * N + n0 + c4];
    tile[r * 65 + c4] = v.x;
    tile[r * 65 + c4 + 1] = v.y;
    tile[r * 65 + c4 + 2] = v.z;
    tile[r * 65 + c4 + 3] = v.w;
  }
  __syncthreads();
#pragma unroll
  for (int rr = 0; rr < 4; ++rr) {
    int r = rr * 16 + rb;  // output row (n-index)
    usx4 hv, lv;
#pragma unroll
    for (int j = 0; j < 4; ++j) {
      float v = tile[(c4 + j) * 65 + r];
      unsigned short h = f2bf(v);
      hv[j] = h;
      lv[j] = f2bf(v - bf2f(h));
    }
    size_t oi = (size_t)(n0 + r) * K + k0 + c4;
    *(usx4*)&hi[oi] = hv;
    if (lo) *(usx4*)&lo[oi] = lv;
  }
  __syncthreads();  // tile reusable
}

// ---------------- prep: Wq/Wk/Wv transpose + bias concat + LN1 ----------------
__global__ __launch_bounds__(256) void prep_kernel(
    const float* __restrict__ Wq, const float* __restrict__ Wk,
    const float* __restrict__ Wv,
    unsigned short* __restrict__ Wcat_hi, unsigned short* __restrict__ Wcat_lo,
    const float* __restrict__ bq, const float* __restrict__ bk,
    const float* __restrict__ bv, float* __restrict__ bias_cat,
    const float* __restrict__ x, const float* __restrict__ ln1s,
    const float* __restrict__ ln1b,
    unsigned short* __restrict__ xn_hi, unsigned short* __restrict__ xn_lo) {
  __shared__ float tile[64 * 65];
  __shared__ float red[2][4];
  int bid = blockIdx.x;
  int tid = threadIdx.x;
  if (bid < 64) {          // Wq (hi+lo)
    tr64(Wq, Wcat_hi, Wcat_lo, 512, 512, bid, tid, tile);
    return;
  }
  if (bid < 128) {         // Wk (hi+lo)
    tr64(Wk, Wcat_hi + 512 * 512, Wcat_lo + 512 * 512, 512, 512, bid - 64, tid, tile);
    return;
  }
  if (bid < 192) {         // Wv (hi only)
    tr64(Wv, Wcat_hi + 1024 * 512, nullptr, 512, 512, bid - 128, tid, tile);
    return;
  }
  if (bid == 192) {        // bias concat
    for (int i = tid; i < 512; i += 256) {
      bias_cat[i] = bq[i];
      bias_cat[512 + i] = bk[i];
      bias_cat[1024 + i] = bv[i];
    }
    return;
  }
  // LN1 row
  int row = bid - 193;
  const float* xr = x + (size_t)row * DIMn;
  float2 xv = *(const float2*)(xr + tid * 2);
  float s  = xv.x + xv.y;
  float s2 = xv.x * xv.x + xv.y * xv.y;
  s = wsum(s); s2 = wsum(s2);
  int wv = tid >> 6;
  if ((tid & 63) == 0) { red[0][wv] = s; red[1][wv] = s2; }
  __syncthreads();
  s  = red[0][0] + red[0][1] + red[0][2] + red[0][3];
  s2 = red[1][0] + red[1][1] + red[1][2] + red[1][3];
  float mean = s * (1.f / DIMn);
  float var  = s2 * (1.f / DIMn) - mean * mean;
  float rstd = rsqrtf(var + 1e-6f);
  int d = tid * 2;
  float2 gv = *(const float2*)(ln1s + d);
  float2 bv2 = *(const float2*)(ln1b + d);
  float o0 = (xv.x - mean) * rstd * gv.x + bv2.x;
  float o1 = (xv.y - mean) * rstd * gv.y + bv2.y;
  size_t idx = (size_t)row * DIMn + d;
  unsigned short h0 = f2bf(o0), h1 = f2bf(o1);
  ushort2 hv; hv.x = h0; hv.y = h1;
  *(ushort2*)(xn_hi + idx) = hv;
  ushort2 lv; lv.x = f2bf(o0 - bf2f(h0)); lv.y = f2bf(o1 - bf2f(h1));
  *(ushort2*)(xn_lo + idx) = lv;
}

// ---------------- LayerNorm -> bf16 (plain) ----------------
__global__ __launch_bounds__(256) void ln_kernel(const float* __restrict__ x,
                                                 const float* __restrict__ g,
                                                 const float* __restrict__ be,
                                                 unsigned short* __restrict__ yhi) {
  __shared__ float red[2][4];
  int row = blockIdx.x;
  int tid = threadIdx.x;
  const float* xr = x + (size_t)row * DIMn;
  float2 xv = *(const float2*)(xr + tid * 2);
  float s  = xv.x + xv.y;
  float s2 = xv.x * xv.x + xv.y * xv.y;
  s = wsum(s); s2 = wsum(s2);
  int wv = tid >> 6;
  if ((tid & 63) == 0) { red[0][wv] = s; red[1][wv] = s2; }
  __syncthreads();
  s  = red[0][0] + red[0][1] + red[0][2] + red[0][3];
  s2 = red[1][0] + red[1][1] + red[1][2] + red[1][3];
  float mean = s * (1.f / DIMn);
  float var  = s2 * (1.f / DIMn) - mean * mean;
  float rstd = rsqrtf(var + 1e-6f);
  int d = tid * 2;
  float2 gv = *(const float2*)(g + d);
  float2 bv = *(const float2*)(be + d);
  float o0 = (xv.x - mean) * rstd * gv.x + bv.x;
  float o1 = (xv.y - mean) * rstd * gv.y + bv.y;
  size_t idx = (size_t)row * DIMn + d;
  ushort2 hv; hv.x = f2bf(o0); hv.y = f2bf(o1);
  *(ushort2*)(yhi + idx) = hv;
}

// ---------------- plain bf16 MFMA GEMM, double-buffered, swizzled (as R7) --------------
template <int BM, int BN, int BKT, int EPI, int OUTBF16>
__global__ __launch_bounds__(256) void gemm_db(
    const unsigned short* __restrict__ Ahi,
    const unsigned short* __restrict__ Bhi,
    const float* __restrict__ bias, const float* __restrict__ res,
    void* __restrict__ outp, int M, int N, int K) {
  constexpr int FI = BM / 32, FJ = BN / 32;
  constexpr int AE = BM * BKT, BE = BN * BKT;
  constexpr int CPR = BKT / 8;
  constexpr int ACH = BM * CPR, BCH = BN * CPR;
  constexpr int CST = BN + 4;
  constexpr int STG = AE + BE;
  constexpr int SMEM_EPI = BM * CST * 2;
  constexpr int SMEM_N = (2 * STG > SMEM_EPI) ? 2 * STG : SMEM_EPI;
  __shared__ __align__(16) unsigned short smem[SMEM_N];

  int tid = threadIdx.x;
  int lane = tid & 63;
  int wid = tid >> 6;
  int wm = (wid >> 1) * (BM / 2), wn = (wid & 1) * (BN / 2);
  int bm = blockIdx.y * BM, bn = blockIdx.x * BN;
  int m16 = lane & 15, kg = lane >> 4;

  floatx4 acc[FI][FJ];
#pragma unroll
  for (int i = 0; i < FI; ++i)
#pragma unroll
    for (int j = 0; j < FJ; ++j) { floatx4 z = {0.f, 0.f, 0.f, 0.f}; acc[i][j] = z; }

  const unsigned short* aph = Ahi + (size_t)bm * K;
  const unsigned short* bph = Bhi + (size_t)bn * K;

  auto stage = [&](int k0, unsigned short* As, unsigned short* Bs) {
    for (int c = tid; c < ACH; c += 256) {
      int row = c / CPR, ci = c % CPR;
      int sci = ci ^ (row & 7);
      glds16(aph + (size_t)row * K + k0 + sci * 8, As + c * 8);
    }
    for (int c = tid; c < BCH; c += 256) {
      int row = c / CPR, ci = c % CPR;
      int sci = ci ^ (row & 7);
      glds16(bph + (size_t)row * K + k0 + sci * 8, Bs + c * 8);
    }
  };

  const int NT = K / BKT;
  stage(0, smem, smem + AE);
  __syncthreads();
  int cur = 0;
  for (int t = 0; t < NT; ++t) {
    unsigned short* As = smem + cur * STG;
    unsigned short* Bs = As + AE;
    int nxt = cur ^ 1;
    if (t + 1 < NT) stage((t + 1) * BKT, smem + nxt * STG, smem + nxt * STG + AE);
#pragma unroll
    for (int ks = 0; ks < BKT / 32; ++ks) {
      short8 ah[FI], bh[FJ];
#pragma unroll
      for (int i = 0; i < FI; ++i) {
        int r = wm + i * 16 + m16;
        ah[i] = *(const short8*)&As[r * BKT + (((ks * 4 + kg) ^ (r & 7)) << 3)];
      }
#pragma unroll
      for (int j = 0; j < FJ; ++j) {
        int r = wn + j * 16 + m16;
        bh[j] = *(const short8*)&Bs[r * BKT + (((ks * 4 + kg) ^ (r & 7)) << 3)];
      }
#pragma unroll
      for (int i = 0; i < FI; ++i)
#pragma unroll
        for (int j = 0; j < FJ; ++j)
          acc[i][j] = __builtin_amdgcn_mfma_f32_16x16x32_bf16(ah[i], bh[j], acc[i][j], 0, 0, 0);
    }
    __syncthreads();
    cur = nxt;
  }

  float* Cs = (float*)smem;
#pragma unroll
  for (int i = 0; i < FI; ++i)
#pragma unroll
    for (int j = 0; j < FJ; ++j)
#pragma unroll
      for (int r = 0; r < 4; ++r)
        Cs[(wm + i * 16 + kg * 4 + r) * CST + wn + j * 16 + m16] = acc[i][j][r];
  __syncthreads();
  constexpr int TOT = BM * BN / 4;
  for (int t = tid; t < TOT; t += 256) {
    int row = (t << 2) / BN;
    int col = (t << 2) & (BN - 1);
    fx4 v = *(const fx4*)&Cs[row * CST + col];
    fx4 bs = *(const fx4*)&bias[bn + col];
    v = v + bs;
    size_t gidx = (size_t)(bm + row) * N + bn + col;
    if constexpr (EPI == 1) {
      fx4 rr = *(const fx4*)&res[gidx];
      v = v + rr;
    }
    if constexpr (EPI == 2) {
      v.x = gelu_tanh(v.x); v.y = gelu_tanh(v.y);
      v.z = gelu_tanh(v.z); v.w = gelu_tanh(v.w);
    }
    if constexpr (OUTBF16) {
      usx4 h;
      h.x = f2bf(v.x); h.y = f2bf(v.y); h.z = f2bf(v.z); h.w = f2bf(v.w);
      *(usx4*)((unsigned short*)outp + gidx) = h;
    } else {
      *(fx4*)((float*)outp + gidx) = v;
    }
  }
}

// ---------------- QKV GEMM (mixed grid): GEMM blocks + Wo/W1/W2 transpose blocks ------
// bid < 768: hybrid split-bf16 GEMM (as R7, swizzled).  bid >= 768: 64x64 transposes.
__global__ __launch_bounds__(256) void qkv_gemm(
    const unsigned short* __restrict__ Ahi, const unsigned short* __restrict__ Alo,
    const unsigned short* __restrict__ Bhi, const unsigned short* __restrict__ Blo,
    const float* __restrict__ bias, float* __restrict__ outp,
    const float* __restrict__ Wo, const float* __restrict__ W1,
    const float* __restrict__ W2,
    unsigned short* __restrict__ Wo_t, unsigned short* __restrict__ W1_t,
    unsigned short* __restrict__ W2_t) {
  constexpr int BM = 64, BN = 64, BKT = 32, K = 512, N = QKVS;
  constexpr int FI = 2, FJ = 2;
  constexpr int AE = BM * BKT, BE = BN * BKT;   // 2048 shorts each
  constexpr int CST = BN + 4;
  constexpr int STG = 2 * (AE + BE);            // 8192 shorts
  constexpr int SMEM_EPI = BM * CST * 2;
  constexpr int SMEM_N = (2 * STG > SMEM_EPI) ? 2 * STG : SMEM_EPI;  // 16384 shorts = 32 KB
  __shared__ __align__(16) unsigned short smem[SMEM_N];

  int tid = threadIdx.x;
  int bid = blockIdx.x;

  if (bid >= 768) {  // backfilled weight transposes (consumers are later launches)
    float* tile = (float*)smem;  // 64*65*4 = 16640 B < 32 KB
    int tix = bid - 768;
    if (tix < 64)       tr64(Wo, Wo_t, nullptr, 512, 512, tix, tid, tile);
    else if (tix < 320) tr64(W1, W1_t, nullptr, 512, 2048, tix - 64, tid, tile);
    else                tr64(W2, W2_t, nullptr, 2048, 512, tix - 320, tid, tile);
    return;
  }

  int lane = tid & 63;
  int wid = tid >> 6;
  int wm = (wid >> 1) * 32, wn = (wid & 1) * 32;
  int bm = (bid / 24) * BM, bn = (bid % 24) * BN;
  int m16 = lane & 15, kg = lane >> 4;
  bool dos = bn < 1024;  // split precision for Q,K only

  floatx4 acc[FI][FJ];
#pragma unroll
  for (int i = 0; i < FI; ++i)
#pragma unroll
    for (int j = 0; j < FJ; ++j) { floatx4 z = {0.f, 0.f, 0.f, 0.f}; acc[i][j] = z; }

  const unsigned short* aph = Ahi + (size_t)bm * K;
  const unsigned short* bph = Bhi + (size_t)bn * K;
  const unsigned short* apl = Alo + (size_t)bm * K;
  const unsigned short* bpl = Blo + (size_t)bn * K;

  auto stage = [&](int k0, unsigned short* buf) {
    {
      int c = tid;
      int row = c >> 2, ci = c & 3;
      int sci = ci ^ ((row >> 1) & 3);
      glds16(aph + (size_t)row * K + k0 + sci * 8, buf + c * 8);
      if (dos) glds16(apl + (size_t)row * K + k0 + sci * 8, buf + AE + c * 8);
    }
    {
      int c = tid;
      int row = c >> 2, ci = c & 3;
      int sci = ci ^ ((row >> 1) & 3);
      glds16(bph + (size_t)row * K + k0 + sci * 8, buf + 2 * AE + c * 8);
      if (dos) glds16(bpl + (size_t)row * K + k0 + sci * 8, buf + 2 * AE + BE + c * 8);
    }
  };

  const int NT = K / BKT;  // 16
  stage(0, smem);
  __syncthreads();
  int cur = 0;
  for (int t = 0; t < NT; ++t) {
    unsigned short* buf = smem + cur * STG;
    unsigned short* AsHi = buf;
    unsigned short* AsLo = buf + AE;
    unsigned short* BsHi = buf + 2 * AE;
    unsigned short* BsLo = buf + 2 * AE + BE;
    int nxt = cur ^ 1;
    if (t + 1 < NT) stage((t + 1) * BKT, smem + nxt * STG);

    short8 ah[FI], bh[FJ], al[FI], bl[FJ];
#pragma unroll
    for (int i = 0; i < FI; ++i) {
      int r = wm + i * 16 + m16;
      int off = r * BKT + ((kg ^ ((r >> 1) & 3)) << 3);
      ah[i] = *(const short8*)&AsHi[off];
      if (dos) al[i] = *(const short8*)&AsLo[off];
    }
#pragma unroll
    for (int j = 0; j < FJ; ++j) {
      int r = wn + j * 16 + m16;
      int off = r * BKT + ((kg ^ ((r >> 1) & 3)) << 3);
      bh[j] = *(const short8*)&BsHi[off];
      if (dos) bl[j] = *(const short8*)&BsLo[off];
    }
#pragma unroll
    for (int i = 0; i < FI; ++i)
#pragma unroll
      for (int j = 0; j < FJ; ++j) {
        acc[i][j] = __builtin_amdgcn_mfma_f32_16x16x32_bf16(ah[i], bh[j], acc[i][j], 0, 0, 0);
        if (dos) {
          acc[i][j] = __builtin_amdgcn_mfma_f32_16x16x32_bf16(al[i], bh[j], acc[i][j], 0, 0, 0);
          acc[i][j] = __builtin_amdgcn_mfma_f32_16x16x32_bf16(ah[i], bl[j], acc[i][j], 0, 0, 0);
        }
      }
    __syncthreads();
    cur = nxt;
  }

  float* Cs = (float*)smem;
#pragma unroll
  for (int i = 0; i < FI; ++i)
#pragma unroll
    for (int j = 0; j < FJ; ++j)
#pragma unroll
      for (int r = 0; r < 4; ++r)
        Cs[(wm + i * 16 + kg * 4 + r) * CST + wn + j * 16 + m16] = acc[i][j][r];
  __syncthreads();
  constexpr int TOT = BM * BN / 4;
  for (int t = tid; t < TOT; t += 256) {
    int row = (t << 2) / BN;
    int col = (t << 2) & (BN - 1);
    fx4 v = *(const fx4*)&Cs[row * CST + col];
    fx4 bs = *(const fx4*)&bias[bn + col];
    v = v + bs;
    size_t gidx = (size_t)(bm + row) * N + bn + col;
    *(fx4*)(outp + gidx) = v;
  }
}

// ---------------- fused hash+RoPE+expmap0 + windowed Poincare attention ----------------
__global__ __launch_bounds__(512) void attn_fused(const float* __restrict__ qkv,
                                                  const float* __restrict__ fcos,
                                                  const float* __restrict__ fsin,
                                                  const float* __restrict__ cvec,
                                                  const float* __restrict__ geo,
                                                  const float* __restrict__ hash,
                                                  unsigned short* __restrict__ attn_out) {
  __shared__ unsigned short Qhi[32][72], Qlo[32][72];   // pad 72: 2-way aliasing only
  __shared__ unsigned short Khi[96][72], Klo[96][72];
  __shared__ unsigned short Vt[64][104];                // V^T [d][key], bf16
  __shared__ unsigned short Pb[32][104];                // softmax weights [query][key]
  __shared__ float Sf[32][97];
  __shared__ float x2s[32], bxs[32], y2s[96], gys[96];

  int tid = threadIdx.x, lane = tid & 63, wv = tid >> 6;  // wv in [0,8)
  int bid = blockIdx.x;  // 512 = B*NH*(N/32)
  int nt = bid & 31, h = (bid >> 5) & 7, b = bid >> 8;
  int n0 = nt * 32;
  float c = cvec[b];
  float sqc = sqrtf(c);
  float rsqc = 1.f / sqc;
  float gs = geo[h];
  int dr = lane & 31;
  bool hih = lane >= 32;
  const float LOG9 = 2.1972245773362196f;
  float hofr = hash[h * HDn + dr] * LOG9;
  float hofi = hash[h * HDn + dr + 32] * LOG9;

  for (int i = tid; i < 32 * 52; i += 512) ((uint32_t*)Pb)[i] = 0u;

  // --- stage Q (4 rows/wave) ---
#pragma unroll
  for (int i = 0; i < 4; ++i) {
    int q = wv * 4 + i;
    int n = n0 + q;
    size_t bas = (size_t)(b * Nn + n) * QKVS + h * HDn;
    float qr = qkv[bas + dr] + hofr;
    float qi = qkv[bas + dr + 32] + hofi;
    float cs = fcos[n * 32 + dr], sn = fsin[n * 32 + dr];
    float qv = hih ? (qr * sn + qi * cs) : (qr * cs - qi * sn);
    float nq = sqrtf(wsum(qv * qv));
    float sq = fmaxf(nq, EPSF);
    float t = sqc * sq;
    float em = expf(-2.f * t);
    float opem = 1.f + em;
    float mag = ((1.f - em) / opem) * rsqc;
    float sech2 = 4.f * em / (opem * opem);
    float oq = (nq < EPSF) ? 0.f : mag * (qv / sq);
    unsigned short hh = f2bf(oq);
    Qhi[q][lane] = hh;
    Qlo[q][lane] = f2bf(oq - bf2f(hh));
    if (lane == 0) {
      x2s[q] = (nq < EPSF) ? 0.f : mag * mag;
      bxs[q] = (nq < EPSF) ? 1.f : sech2;
    }
  }
  // --- stage K (12 rows/wave) + V^T ---
#pragma unroll 4
  for (int i = 0; i < 12; ++i) {
    int r = wv * 12 + i;
    int gi = n0 - 64 + r;
    float ok = 0.f, vf = 0.f, y2 = 0.f, gy = 1.f;
    if (gi >= 0) {
      size_t bas = (size_t)(b * Nn + gi) * QKVS + h * HDn;
      float kr = qkv[bas + 512 + dr];
      float ki = qkv[bas + 512 + dr + 32];
      vf = qkv[bas + 1024 + lane];
      float cs = fcos[gi * 32 + dr], sn = fsin[gi * 32 + dr];
      float kv = hih ? (kr * sn + ki * cs) : (kr * cs - ki * sn);
      float nk = sqrtf(wsum(kv * kv));
      float sk = fmaxf(nk, EPSF);
      float t = sqc * sk;
      float em = expf(-2.f * t);
      float opem = 1.f + em;
      float mag = ((1.f - em) / opem) * rsqc;
      float sech2 = 4.f * em / (opem * opem);
      ok = (nk < EPSF) ? 0.f : mag * (kv / sk);
      y2 = (nk < EPSF) ? 0.f : mag * mag;
      gy = (nk < EPSF) ? 1.f : sech2;
    }
    unsigned short hh = f2bf(ok);
    Khi[r][lane] = hh;
    Klo[r][lane] = f2bf(ok - bf2f(hh));
    Vt[lane][r] = f2bf(vf);
    if (lane == 0) { y2s[r] = y2; gys[r] = gy; }
  }
  __syncthreads();

  // --- S = Q K^T via split-bf16 MFMA: 12 tile-units (2 mt x 6 nt) over 8 waves ---
  int m16 = lane & 15, kg = lane >> 4;
#pragma unroll
  for (int uu = 0; uu < 2; ++uu) {
    int u = wv + uu * 8;
    if (u < 12) {
      int mt = u / 6, ntile = u % 6;
      floatx4 acc = {0.f, 0.f, 0.f, 0.f};
#pragma unroll
      for (int ks = 0; ks < 2; ++ks) {
        short8 ah = *(const short8*)&Qhi[mt * 16 + m16][ks * 32 + kg * 8];
        short8 al = *(const short8*)&Qlo[mt * 16 + m16][ks * 32 + kg * 8];
        short8 bh = *(const short8*)&Khi[ntile * 16 + m16][ks * 32 + kg * 8];
        short8 bl = *(const short8*)&Klo[ntile * 16 + m16][ks * 32 + kg * 8];
        acc = __builtin_amdgcn_mfma_f32_16x16x32_bf16(ah, bh, acc, 0, 0, 0);
        acc = __builtin_amdgcn_mfma_f32_16x16x32_bf16(al, bh, acc, 0, 0, 0);
        acc = __builtin_amdgcn_mfma_f32_16x16x32_bf16(ah, bl, acc, 0, 0, 0);
      }
#pragma unroll
      for (int r = 0; r < 4; ++r) Sf[mt * 16 + kg * 4 + r][ntile * 16 + m16] = acc[r];
    }
  }
  __syncthreads();

  // --- scores + softmax (sc<=0 analytically; no max-subtraction needed) ---
#pragma unroll
  for (int i = 0; i < 4; ++i) {
    int nl = wv * 4 + i;
    int r = nl + 1 + lane;
    float xy = Sf[nl][r];
    float x2 = x2s[nl], y2 = y2s[r];
    float bx = bxs[nl], gy = gys[r];

    float den = fmaf(c * c * x2, y2, fmaf(-2.f * c, xy, 1.f));
    den = fmaxf(den, EPSF);
    float rden = 1.f / den;
    float s2 = fmaxf(x2 - 2.f * xy + y2, 0.f);
    float z = sqrtf(c * s2 * rden);
    float omz2 = bx * gy * rden;
    float opz = 1.f + fminf(z, 1.f);
    float ratio = fminf(opz * opz / omz2, 1.9999999e7f);
    float sc = -gs * logf(ratio) * rsqc;

    float e = expf(sc);
    float se = wsum(e);
    Pb[nl][r] = f2bf(e / se);
  }
  __syncthreads();

  // --- PV via MFMA: 8 tile-units (2 mt x 4 nt), one per wave ---
  {
    int mt = wv >> 2, ntile = wv & 3;
    floatx4 acc = {0.f, 0.f, 0.f, 0.f};
#pragma unroll
    for (int ks = 0; ks < 3; ++ks) {
      short8 a = *(const short8*)&Pb[mt * 16 + m16][ks * 32 + kg * 8];
      short8 bb = *(const short8*)&Vt[ntile * 16 + m16][ks * 32 + kg * 8];
      acc = __builtin_amdgcn_mfma_f32_16x16x32_bf16(a, bb, acc, 0, 0, 0);
    }
#pragma unroll
    for (int r = 0; r < 4; ++r) {
      int qrow = mt * 16 + kg * 4 + r;
      int d = ntile * 16 + m16;
      attn_out[(size_t)(b * Nn + n0 + qrow) * DIMn + h * HDn + d] = f2bf(acc[r]);
    }
  }
}

// ---------------- launcher ----------------
extern "C" void kernel_launch(void* const* d_in, const int* in_sizes, int n_in,
                              void* d_out, int out_size, void* d_ws, size_t ws_size,
                              hipStream_t stream) {
  const float* x    = (const float*)d_in[0];
  const float* fcos = (const float*)d_in[1];
  const float* fsin = (const float*)d_in[2];
  const float* cvec = (const float*)d_in[3];
  const float* Wq = (const float*)d_in[4];  const float* bq = (const float*)d_in[5];
  const float* Wk = (const float*)d_in[6];  const float* bk = (const float*)d_in[7];
  const float* Wv = (const float*)d_in[8];  const float* bv = (const float*)d_in[9];
  const float* Wo = (const float*)d_in[10]; const float* bo = (const float*)d_in[11];
  const float* W1 = (const float*)d_in[12]; const float* b1 = (const float*)d_in[13];
  const float* W2 = (const float*)d_in[14]; const float* b2 = (const float*)d_in[15];
  const float* ln1s = (const float*)d_in[16]; const float* ln1b = (const float*)d_in[17];
  const float* ln2s = (const float*)d_in[18]; const float* ln2b = (const float*)d_in[19];
  const float* geo  = (const float*)d_in[20]; const float* hash = (const float*)d_in[21];
  float* out = (float*)d_out;
  char* base = (char*)d_ws;

  unsigned short* Wcat_hi = (unsigned short*)(base + 0);         // 1536x512 bf16
  unsigned short* Wcat_lo = (unsigned short*)(base + 1572864);
  unsigned short* Wo_t    = (unsigned short*)(base + 3145728);   // 512x512
  unsigned short* W1_t    = (unsigned short*)(base + 3670016);   // 2048x512
  unsigned short* W2_t    = (unsigned short*)(base + 5767168);   // 512x2048
  unsigned short* xn_hi   = (unsigned short*)(base + 7864320);   // 2048x512
  unsigned short* xn_lo   = (unsigned short*)(base + 9961472);
  float*          qkv     = (float*)(base + 12058624);           // 2048x1536 f32
  unsigned short* attnb   = (unsigned short*)(base + 7864320);   // reuse xn_hi
  float*          xout    = (float*)(base + 9961472);            // 2048x512 f32 (reuse)
  unsigned short* hbuf    = (unsigned short*)(base + 14155776);  // 2048x512
  unsigned short* mid     = (unsigned short*)(base + 16252928);  // 2048x2048
  float*          bias_cat= (float*)(base + 24641536);           // 1536 f32

  const int M = Bn * Nn;  // 2048

  // 1) Wq/Wk/Wv transpose (64x64 tiles) + bias concat + LN1
  prep_kernel<<<193 + M, 256, 0, stream>>>(Wq, Wk, Wv, Wcat_hi, Wcat_lo,
                                           bq, bk, bv, bias_cat,
                                           x, ln1s, ln1b, xn_hi, xn_lo);
  // 2) QKV GEMM (768 blocks) + backfilled Wo/W1/W2 transposes (576 blocks)
  qkv_gemm<<<768 + 576, 256, 0, stream>>>(
      xn_hi, xn_lo, Wcat_hi, Wcat_lo, bias_cat, qkv,
      Wo, W1, W2, Wo_t, W1_t, W2_t);
  // 3) fused rope + windowed Poincare attention -> attnb bf16
  attn_fused<<<Bn * NHn * (Nn / 32), 512, 0, stream>>>(qkv, fcos, fsin, cvec, geo, hash, attnb);
  // 4) Wo + residual(x) -> xout f32; 32x32 dbuf + swizzle
  gemm_db<32, 32, 64, 1, 0><<<dim3(DIMn / 32, M / 32), 256, 0, stream>>>(
      attnb, Wo_t, bo, x, xout, M, DIMn, 512);
  // 5) LN2 -> hbuf bf16
  ln_kernel<<<M, 256, 0, stream>>>(xout, ln2s, ln2b, hbuf);
  // 6) FFN1 + gelu -> mid bf16; 64x64 dbuf + swizzle
  gemm_db<64, 64, 64, 2, 1><<<dim3(2048 / 64, M / 64), 256, 0, stream>>>(
      hbuf, W1_t, b1, nullptr, mid, M, 2048, 512);
  // 7) FFN2 + residual(xout) -> out f32; 32x32 dbuf + swizzle
  gemm_db<32, 32, 64, 1, 0><<<dim3(DIMn / 32, M / 32), 256, 0, stream>>>(
      mid, W2_t, b2, xout, out, M, DIMn, 2048);
}